// Round 7
// baseline (451.794 us; speedup 1.0000x reference)
//
#include <hip/hip_runtime.h>
#include <hip/hip_bf16.h>
#include <math.h>

#define Hn 6
#define Bn 512
#define Dn 2048
#define Cn 1000
#define Cpad 1024
#define TAUv 0.5f
#define KSPLIT 2
#define KPER (Dn / KSPLIT)   // 1024 k per kz slice
#define NIT (KPER / 32)      // 32 k-iters per block
#define NBLK 768             // 16 x 4 x 12 grid, 3 blocks/CU x 256 CU: all resident

typedef unsigned int u32;
typedef unsigned short u16;
typedef __attribute__((ext_vector_type(8))) short short8;
typedef __attribute__((ext_vector_type(4))) float f32x4;

union FragU { u32 d[4]; short8 s; };

// pack two fp32 -> one dword of bf16 (RNE, f0 in low half; lowers to v_cvt_pk_bf16_f32)
__device__ __forceinline__ u32 cvt_pk2(float f0, float f1) {
  union { __hip_bfloat162 h; u32 u; } cv;
  cv.h = __float22bfloat162_rn(make_float2(f0, f1));
  return cv.u;
}

// 8 fp32 -> hi short8 (bf16) + lo short8 (bf16 of residual). RNE both.
__device__ __forceinline__ void pack8f(const float* f, FragU& hi, FragU& lo) {
  float r[8];
#pragma unroll
  for (int i = 0; i < 4; ++i) {
    const u32 d = cvt_pk2(f[2 * i], f[2 * i + 1]);
    hi.d[i] = d;
    r[2 * i]     = f[2 * i]     - __uint_as_float(d << 16);
    r[2 * i + 1] = f[2 * i + 1] - __uint_as_float(d & 0xffff0000u);
  }
#pragma unroll
  for (int i = 0; i < 4; ++i) lo.d[i] = cvt_pk2(r[2 * i], r[2 * i + 1]);
}

// async global->LDS DMA, 16 B/lane; LDS dest = wave-uniform base + lane*16 (linear!)
__device__ __forceinline__ void dma16(const void* g, void* l) {
  __builtin_amdgcn_global_load_lds(
      (const __attribute__((address_space(1))) u32*)g,
      (__attribute__((address_space(3))) u32*)l, 16, 0, 0);
}

// grid-wide barrier for an all-resident grid: release fence + ticket + spin.
// Protocol proven in R6 (threadfence + atomic ticket, cross-XCD reduce passed).
__device__ __forceinline__ void grid_barrier(u32* cnt, int tid) {
  __syncthreads();                       // block stores drained (vmcnt before s_barrier)
  if (tid == 0) {
    __threadfence();                     // release: this block's stores visible
    atomicAdd(cnt, 1u);
    while (__hip_atomic_load(cnt, __ATOMIC_RELAXED, __HIP_MEMORY_SCOPE_AGENT) < (u32)NBLK)
      __builtin_amdgcn_s_sleep(8);
  }
  __syncthreads();
  __threadfence();                       // acquire: other blocks' stores visible
}

// ============ ONE persistent kernel: GEMM -> barrier -> stats -> barrier -> pick ============
__global__ __launch_bounds__(256, 3) void fused_k(
    const float* __restrict__ feats, const float* __restrict__ W,
    const float* __restrict__ bias, float* logits,
    const int* __restrict__ y, float* __restrict__ out,
    float* __restrict__ out_exit, float* __restrict__ loss_b,
    float* __restrict__ corr_b, float* __restrict__ msA,
    float* __restrict__ ssA, u32* cnts, float* __restrict__ scalars)
{
  const int h  = blockIdx.z >> 1;
  const int kz = blockIdx.z & 1;
  const int m0 = blockIdx.y * 128;
  const int n0 = blockIdx.x * 64;
  const int bid = blockIdx.x + 16 * (blockIdx.y + 4 * blockIdx.z);
  const int t = threadIdx.x, lane = t & 63, w = t >> 6;

  __shared__ __align__(16) float lds[2][6144];   // 2 x (A 16KB | B 8KB) = 48 KB

  // ================= phase 1: split-bf16 MFMA GEMM (unchanged, R6) =================
  const int rA = (w & 1) * 64 + (lane >> 3);
  const int qA = (lane & 7) ^ ((lane >> 3) & 7);
  const float* gsrcA = feats + ((size_t)(h * Bn + m0 + rA)) * Dn + kz * KPER + qA * 4;
  const size_t gciA = (size_t)8 * Dn;
  const int dstA = w * 8192 + lane * 16;

  const int kb = (w - 2) * 16 + (lane >> 4);
  const int cB = lane & 15;
  const float* Wrow = W + ((size_t)h * Dn + kz * KPER) * Cn;
  const int dstB = 16384 + (w - 2) * 4096 + lane * 16;

  const int fl = lane & 15, fq = lane >> 4;
  const int wm = (w & 1) * 64, wn = (w >> 1) * 32;
  const int sxor = fl & 7;

  f32x4 acc[4][2];
#pragma unroll
  for (int i = 0; i < 4; ++i)
#pragma unroll
    for (int j = 0; j < 2; ++j) acc[i][j] = (f32x4){0.f, 0.f, 0.f, 0.f};

#define STAGE(TILE)                                                                   \
  {                                                                                   \
    char* sb = (char*)&lds[(TILE) & 1][0];                                            \
    if (w < 2) {                                                                      \
      const float* g = gsrcA + (size_t)(TILE) * 32;                                   \
      _Pragma("unroll")                                                               \
      for (int i = 0; i < 8; ++i) dma16(g + i * gciA, sb + dstA + i * 1024);          \
    } else {                                                                          \
      const size_t kt0 = (size_t)(TILE) * 32;                                         \
      _Pragma("unroll")                                                               \
      for (int i = 0; i < 4; ++i) {                                                   \
        const int kl = kb + 4 * i;                                                    \
        const int pc = cB ^ (((kl >> 3) & 1) << 2);                                   \
        int col = n0 + pc * 4;                                                        \
        col = (col + 3 < Cn) ? col : (Cn - 4);                                        \
        dma16(Wrow + (kt0 + kl) * Cn + col, sb + dstB + i * 1024);                    \
      }                                                                               \
    }                                                                                 \
  }

#define WAITCUR()                                                                     \
  {                                                                                   \
    if (w < 2) asm volatile("s_waitcnt vmcnt(8)" ::: "memory");                       \
    else       asm volatile("s_waitcnt vmcnt(4)" ::: "memory");                       \
  }

#define COMPUTE_TILE(IT)                                                              \
  {                                                                                   \
    const char*  ab = (const char*)&lds[(IT) & 1][0];                                 \
    const float* bb = (const float*)(ab + 16384);                                     \
    FragU ah[4], al[4];                                                               \
    _Pragma("unroll")                                                                 \
    for (int mt = 0; mt < 4; ++mt) {                                                  \
      const int r = wm + mt * 16 + fl;                                                \
      const float4 v0 = *(const float4*)(ab + r * 128 + ((((fq * 2)    ) ^ sxor) * 16)); \
      const float4 v1 = *(const float4*)(ab + r * 128 + ((((fq * 2) + 1) ^ sxor) * 16)); \
      float f[8] = {v0.x, v0.y, v0.z, v0.w, v1.x, v1.y, v1.z, v1.w};                  \
      pack8f(f, ah[mt], al[mt]);                                                      \
    }                                                                                 \
    _Pragma("unroll")                                                                 \
    for (int nt = 0; nt < 2; ++nt) {                                                  \
      const int n = wn + nt * 16 + fl;                                                \
      const int nsw = ((((n >> 2) ^ ((fq & 1) << 2)) << 2) | (n & 3));                \
      float f[8];                                                                     \
      _Pragma("unroll")                                                               \
      for (int e = 0; e < 8; ++e) f[e] = bb[(fq * 8 + e) * 64 + nsw];                 \
      FragU bh, bl;                                                                   \
      pack8f(f, bh, bl);                                                              \
      _Pragma("unroll")                                                               \
      for (int mt = 0; mt < 4; ++mt) {                                                \
        acc[mt][nt] = __builtin_amdgcn_mfma_f32_16x16x32_bf16(ah[mt].s, bh.s, acc[mt][nt], 0, 0, 0); \
        acc[mt][nt] = __builtin_amdgcn_mfma_f32_16x16x32_bf16(ah[mt].s, bl.s, acc[mt][nt], 0, 0, 0); \
        acc[mt][nt] = __builtin_amdgcn_mfma_f32_16x16x32_bf16(al[mt].s, bh.s, acc[mt][nt], 0, 0, 0); \
      }                                                                               \
    }                                                                                 \
  }

  STAGE(0);

  for (int it = 0; it < NIT - 1; ++it) {
    STAGE(it + 1);
    WAITCUR();
    __builtin_amdgcn_s_barrier();
    __builtin_amdgcn_sched_barrier(0);
    __builtin_amdgcn_s_setprio(1);
    COMPUTE_TILE(it);
    __builtin_amdgcn_s_setprio(0);
    __builtin_amdgcn_sched_barrier(0);
    asm volatile("s_waitcnt lgkmcnt(0)" ::: "memory");
    __builtin_amdgcn_s_barrier();
  }
  asm volatile("s_waitcnt vmcnt(0)" ::: "memory");
  __builtin_amdgcn_s_barrier();
  __builtin_amdgcn_sched_barrier(0);
  __builtin_amdgcn_s_setprio(1);
  COMPUTE_TILE(NIT - 1);
  __builtin_amdgcn_s_setprio(0);
#undef COMPUTE_TILE
#undef WAITCUR
#undef STAGE

  float* part = logits + (size_t)kz * ((size_t)Hn * Bn * Cn);
#pragma unroll
  for (int nt = 0; nt < 2; ++nt) {
    const int col = n0 + wn + nt * 16 + fl;
    if (col >= Cn) continue;
    const float bv = (kz == 0) ? bias[(size_t)h * Cn + col] : 0.f;
#pragma unroll
    for (int mt = 0; mt < 4; ++mt) {
      const int rbase = m0 + wm + mt * 16 + fq * 4;
#pragma unroll
      for (int r = 0; r < 4; ++r)
        part[((size_t)h * Bn + rbase + r) * Cn + col] = acc[mt][nt][r] + bv;
    }
  }

  // ================= grid barrier 1: all logits partials visible =================
  grid_barrier(&cnts[0], t);

  // ================= phase 2: stats — one row per wave (768*4 = 3072 rows) ========
  const size_t S = (size_t)Hn * Bn * Cn;
  {
    const int id = bid * 4 + w;           // h*Bn + b
    const float* p = logits + (size_t)id * Cn;
    float vv[16];
#pragma unroll
    for (int i = 0; i < 4; ++i) {
      const int c4 = i * 256 + lane * 4;
      if (c4 + 3 < Cn) {
        const float4 v0 = *(const float4*)(p + c4);
        const float4 v1 = *(const float4*)(p + S + c4);
        vv[4 * i + 0] = v0.x + v1.x;
        vv[4 * i + 1] = v0.y + v1.y;
        vv[4 * i + 2] = v0.z + v1.z;
        vv[4 * i + 3] = v0.w + v1.w;
      } else {
#pragma unroll
        for (int j = 0; j < 4; ++j) {
          const int c = c4 + j;
          vv[4 * i + j] = (c < Cn) ? p[c] + p[S + c] : -3.4e38f;
        }
      }
    }
    float m = -3.4e38f;
#pragma unroll
    for (int i = 0; i < 16; ++i) m = fmaxf(m, vv[i]);
#pragma unroll
    for (int off = 32; off >= 1; off >>= 1) m = fmaxf(m, __shfl_xor(m, off));
    float s = 0.f;
#pragma unroll
    for (int i = 0; i < 16; ++i) s += (vv[i] > -3.0e38f) ? expf(vv[i] - m) : 0.f;
#pragma unroll
    for (int off = 32; off >= 1; off >>= 1) s += __shfl_xor(s, off);
    if (lane == 0) { msA[id] = m; ssA[id] = s; }
  }

  // ================= grid barrier 2: all stats visible ============================
  grid_barrier(&cnts[1], t);

  // ================= phase 3: route + gather + CE (blocks 0..511) =================
  if (bid < Bn) {
    const int b = bid;
    int first = -1, best = 0;
    float bestc = -3.4e38f;
#pragma unroll
    for (int hh = 0; hh < Hn; ++hh) {
      const float c = 1.0f / ssA[hh * Bn + b];
      if (first < 0 && c >= TAUv) first = hh;
      if (c > bestc) { bestc = c; best = hh; }
    }
    const int ex = (first >= 0) ? first : best;
    const float* p = logits + ((size_t)ex * Bn + b) * Cn;

    const int c4 = t * 4;
    float vv[4] = {-3.4e38f, -3.4e38f, -3.4e38f, -3.4e38f};
    if (c4 + 3 < Cn) {
      const float4 v0 = *(const float4*)(p + c4);
      const float4 v1 = *(const float4*)(p + S + c4);
      vv[0] = v0.x + v1.x;
      vv[1] = v0.y + v1.y;
      vv[2] = v0.z + v1.z;
      vv[3] = v0.w + v1.w;
    }
    float vm = -3.4e38f; int im = 1 << 30;
#pragma unroll
    for (int j = 0; j < 4; ++j) {
      const int c = c4 + j;
      if (c < Cn) {
        out[(size_t)b * Cn + c] = vv[j];
        if (vv[j] > vm) { vm = vv[j]; im = c; }
      }
    }
#pragma unroll
    for (int off = 32; off >= 1; off >>= 1) {
      const float ov = __shfl_xor(vm, off);
      const int   oi = __shfl_xor(im, off);
      if (ov > vm || (ov == vm && oi < im)) { vm = ov; im = oi; }
    }
    __shared__ float rm[4]; __shared__ int ri[4];
    __shared__ u32 tk;
    if (lane == 0) { rm[w] = vm; ri[w] = im; }
    __syncthreads();
    if (t == 0) {
      float bm = rm[0]; int bi = ri[0];
      for (int q = 1; q < 4; ++q)
        if (rm[q] > bm || (rm[q] == bm && ri[q] < bi)) { bm = rm[q]; bi = ri[q]; }
      const int yt = y[b];
      const float ryt = p[yt] + p[S + yt];
      const float lp = ryt - msA[ex * Bn + b] - logf(ssA[ex * Bn + b]);
      out_exit[b] = (float)ex;
      loss_b[b] = -lp;
      corr_b[b] = (bi == yt) ? 1.f : 0.f;
      __threadfence();                   // release before ticket
      tk = atomicAdd(&cnts[2], 1u);
    }
    __syncthreads();

    // ---- last arriving sample-block reduces 512 -> 2 scalars (deterministic) ----
    if (tk == (u32)(Bn - 1)) {
      __threadfence();                   // acquire
      float l = loss_b[t] + loss_b[t + 256];
      float c = corr_b[t] + corr_b[t + 256];
#pragma unroll
      for (int off = 32; off >= 1; off >>= 1) {
        l += __shfl_xor(l, off);
        c += __shfl_xor(c, off);
      }
      __shared__ float sl[4], sc[4];
      if (lane == 0) { sl[w] = l; sc[w] = c; }
      __syncthreads();
      if (t == 0) {
        scalars[0] = (sl[0] + sl[1] + sl[2] + sl[3]) * (1.0f / (float)Bn);
        scalars[1] = (sc[0] + sc[1] + sc[2] + sc[3]) * (1.0f / (float)Bn);
      }
    }
  }
}

extern "C" void kernel_launch(void* const* d_in, const int* in_sizes, int n_in,
                              void* d_out, int out_size, void* d_ws, size_t ws_size,
                              hipStream_t stream) {
  const float* feats = (const float*)d_in[0];   // [H,B,D] fp32
  const float* W     = (const float*)d_in[1];   // [H,D,C] fp32
  const float* bias  = (const float*)d_in[2];   // [H,C]
  const int*   y     = (const int*)d_in[3];     // [B]
  float* out = (float*)d_out;                   // [B*C | B | 1 | 1]

  // ws: logits partials (24,576,000 B) + loss_b[512] + corr_b[512]
  //     + msA[3072] + ssA[3072] + cnts[3]
  float* logits = (float*)d_ws;
  float* loss_b = logits + (size_t)KSPLIT * Hn * Bn * Cn;
  float* corr_b = loss_b + Bn;
  float* msA    = corr_b + Bn;
  float* ssA    = msA + Hn * Bn;
  u32*   cnts   = (u32*)(ssA + Hn * Bn);
  float* out_exit    = out + (size_t)Bn * Cn;
  float* out_scalars = out + (size_t)Bn * Cn + Bn;

  hipMemsetAsync(cnts, 0, 3 * sizeof(u32), stream);   // zero barrier/ticket counters
  fused_k<<<dim3(Cpad / 64, Bn / 128, Hn * KSPLIT), 256, 0, stream>>>(
      feats, W, bias, logits, y, out, out_exit, loss_b, corr_b,
      msA, ssA, cnts, out_scalars);
}

// Round 8
// 193.554 us; speedup vs baseline: 2.3342x; 2.3342x over previous
//
#include <hip/hip_runtime.h>
#include <hip/hip_bf16.h>
#include <math.h>

#define Hn 6
#define Bn 512
#define Dn 2048
#define Cn 1000
#define Cpad 1024
#define TAUv 0.5f
#define KSPLIT 2
#define KPER (Dn / KSPLIT)   // 1024 k per kz slice
#define NIT (KPER / 32)      // 32 k-iters per block
#define NKT (Dn / 32)        // 64 ktiles total

typedef unsigned int u32;
typedef unsigned short u16;
typedef __attribute__((ext_vector_type(8))) short short8;
typedef __attribute__((ext_vector_type(4))) float f32x4;

union FragU { u32 d[4]; short8 s; };

// pack two fp32 -> one dword of bf16 (RNE, f0 in low half; lowers to v_cvt_pk_bf16_f32)
__device__ __forceinline__ u32 cvt_pk2(float f0, float f1) {
  union { __hip_bfloat162 h; u32 u; } cv;
  cv.h = __float22bfloat162_rn(make_float2(f0, f1));
  return cv.u;
}

// 8 fp32 -> hi short8 (bf16) + lo short8 (bf16 of residual). RNE both.
__device__ __forceinline__ void pack8f(const float* f, FragU& hi, FragU& lo) {
  float r[8];
#pragma unroll
  for (int i = 0; i < 4; ++i) {
    const u32 d = cvt_pk2(f[2 * i], f[2 * i + 1]);
    hi.d[i] = d;
    r[2 * i]     = f[2 * i]     - __uint_as_float(d << 16);
    r[2 * i + 1] = f[2 * i + 1] - __uint_as_float(d & 0xffff0000u);
  }
#pragma unroll
  for (int i = 0; i < 4; ++i) lo.d[i] = cvt_pk2(r[2 * i], r[2 * i + 1]);
}

// 8 fp32 -> hi/lo 16B uint4 (same RNE math, vector regs) — for the conv kernel
__device__ __forceinline__ void pack8v(const float* rr, uint4& hv, uint4& lv) {
  FragU h, l;
  pack8f(rr, h, l);
  hv = make_uint4(h.d[0], h.d[1], h.d[2], h.d[3]);
  lv = make_uint4(l.d[0], l.d[1], l.d[2], l.d[3]);
}

// async global->LDS DMA, 16 B/lane; LDS dest = wave-uniform base + lane*16 (linear!)
__device__ __forceinline__ void dma16(const void* g, void* l) {
  __builtin_amdgcn_global_load_lds(
      (const __attribute__((address_space(1))) u32*)g,
      (__attribute__((address_space(3))) u32*)l, 16, 0, 0);
}

// ============ convW_k: W fp32 [H][D][C] -> k-tiled bf16 hi/lo [H][64][4][1024][8] ============
// (R0's proven B-conv path; element (h, k=kt*32+c*8+e, n) -> Bh[h][kt][c][n][e])
__global__ __launch_bounds__(256) void convW_k(
    const float* __restrict__ W, u16* __restrict__ Bh, u16* __restrict__ Bl)
{
  __shared__ float smem[32 * 129];
  const int t  = blockIdx.x;     // ktile 0..63
  const int n0 = blockIdx.y * 128;
  const int h  = blockIdx.z;
  const int tid = threadIdx.x;

#pragma unroll
  for (int i = 0; i < 4; ++i) {
    const int f = i * 256 + tid;           // 0..1023 float4 tasks
    const int k = f >> 5, q = f & 31;
    const int n = n0 + q * 4;
    const float* src = W + ((size_t)h * Dn + t * 32 + k) * Cn;
    float4 v = make_float4(0.f, 0.f, 0.f, 0.f);
    if (n + 3 < Cn) {
      v = *(const float4*)(src + n);
    } else {
      if (n + 0 < Cn) v.x = src[n + 0];
      if (n + 1 < Cn) v.y = src[n + 1];
      if (n + 2 < Cn) v.z = src[n + 2];
      if (n + 3 < Cn) v.w = src[n + 3];
    }
    smem[k * 129 + q * 4 + 0] = v.x; smem[k * 129 + q * 4 + 1] = v.y;
    smem[k * 129 + q * 4 + 2] = v.z; smem[k * 129 + q * 4 + 3] = v.w;
  }
  __syncthreads();
#pragma unroll
  for (int i = 0; i < 2; ++i) {
    const int j = i * 256 + tid;           // 0..511
    const int c = j >> 7, n = j & 127;
    float rr[8];
#pragma unroll
    for (int e = 0; e < 8; ++e) rr[e] = smem[(c * 8 + e) * 129 + n];
    uint4 hv, lv;
    pack8v(rr, hv, lv);
    const size_t o = (((size_t)(h * NKT + t) * 4 + c) * Cpad + n0 + n);
    ((uint4*)Bh)[o] = hv;
    ((uint4*)Bl)[o] = lv;
  }
}

// ============ split-bf16 MFMA GEMM: fused A-pack (fp32 feats), prepacked B ============
// Tile 128(M)x64(N), BK=32, KSPLIT=2. LDS 2 x (A 16KB fp32 | Bh 4KB | Bl 4KB) = 48KB,
// 3 blocks/CU, 768-block 1-D grid with bijective XCD swizzle (768 = 8 x 96).
// T4 pipeline: {issue next-tile DMA; counted vmcnt (A-waves 8, B-waves 4); s_barrier;
// compute; lgkmcnt(0); s_barrier}. A swizzle as before (rule #21, source-side).
// B frags: direct ds_read_b128 of bf16 hi/lo at [fq][n] — no pack, no XOR (bank: 16
// lanes stride 16B -> 8 bank-quads x 2-way = free).
__global__ __launch_bounds__(256, 3) void gemm_k(
    const float* __restrict__ feats, const u16* __restrict__ BhG,
    const u16* __restrict__ BlG, const float* __restrict__ bias,
    float* __restrict__ logits)
{
  // bijective XCD swizzle: consecutive 96-block chunks per XCD
  const int wg = (blockIdx.x & 7) * 96 + (blockIdx.x >> 3);
  const int n0 = (wg & 15) * 64;
  const int m0 = ((wg >> 4) & 3) * 128;
  const int z  = wg >> 6;
  const int h  = z >> 1;
  const int kz = z & 1;
  const int t = threadIdx.x, lane = t & 63, w = t >> 6;

  __shared__ __align__(16) float lds[2][6144];   // 2 x (A 16KB | Bh 4KB | Bl 4KB)

  // A staging (waves 0,1): 8 x 1KB per tile, source pre-swizzled
  const int rA = (w & 1) * 64 + (lane >> 3);
  const int qA = (lane & 7) ^ ((lane >> 3) & 7);
  const float* gsrcA = feats + ((size_t)(h * Bn + m0 + rA)) * Dn + kz * KPER + qA * 4;
  const size_t gciA = (size_t)8 * Dn;
  const int dstA = w * 8192 + lane * 16;

  // B staging (wave 2 -> hi, wave 3 -> lo): 4 x 1KB per tile, n-contiguous slices
  const uint4* bsrcG = (const uint4*)((w == 2) ? BhG : BlG)
                     + ((size_t)h * NKT) * 4 * Cpad + n0 + lane;
  const int dstB = 16384 + (w - 2) * 4096 + lane * 16;

  const int fl = lane & 15, fq = lane >> 4;
  const int wm = (w & 1) * 64, wn = (w >> 1) * 32;
  const int sxor = fl & 7;

  f32x4 acc[4][2];
#pragma unroll
  for (int i = 0; i < 4; ++i)
#pragma unroll
    for (int j = 0; j < 2; ++j) acc[i][j] = (f32x4){0.f, 0.f, 0.f, 0.f};

#define STAGE(TILE)                                                                   \
  {                                                                                   \
    char* sb = (char*)&lds[(TILE) & 1][0];                                            \
    if (w < 2) {                                                                      \
      const float* g = gsrcA + (size_t)(TILE) * 32;                                   \
      _Pragma("unroll")                                                               \
      for (int i = 0; i < 8; ++i) dma16(g + i * gciA, sb + dstA + i * 1024);          \
    } else {                                                                          \
      const int kt = kz * NIT + (TILE);                                               \
      const uint4* g = bsrcG + (size_t)(kt * 4) * Cpad;                               \
      _Pragma("unroll")                                                               \
      for (int i = 0; i < 4; ++i) dma16(g + (size_t)i * Cpad, sb + dstB + i * 1024);  \
    }                                                                                 \
  }

#define WAITCUR()                                                                     \
  {                                                                                   \
    if (w < 2) asm volatile("s_waitcnt vmcnt(8)" ::: "memory");                       \
    else       asm volatile("s_waitcnt vmcnt(4)" ::: "memory");                       \
  }

#define COMPUTE_TILE(IT)                                                              \
  {                                                                                   \
    const char* ab  = (const char*)&lds[(IT) & 1][0];                                 \
    const u16*  bbh = (const u16*)(ab + 16384);                                       \
    const u16*  bbl = (const u16*)(ab + 16384 + 4096);                                \
    FragU ah[4], al[4];                                                               \
    _Pragma("unroll")                                                                 \
    for (int mt = 0; mt < 4; ++mt) {                                                  \
      const int r = wm + mt * 16 + fl;                                                \
      const float4 v0 = *(const float4*)(ab + r * 128 + ((((fq * 2)    ) ^ sxor) * 16)); \
      const float4 v1 = *(const float4*)(ab + r * 128 + ((((fq * 2) + 1) ^ sxor) * 16)); \
      float f[8] = {v0.x, v0.y, v0.z, v0.w, v1.x, v1.y, v1.z, v1.w};                  \
      pack8f(f, ah[mt], al[mt]);                                                      \
    }                                                                                 \
    _Pragma("unroll")                                                                 \
    for (int nt = 0; nt < 2; ++nt) {                                                  \
      const int n = wn + nt * 16 + fl;                                                \
      FragU bh, bl;                                                                   \
      bh.s = *(const short8*)(bbh + (size_t)(fq * 64 + n) * 8);                       \
      bl.s = *(const short8*)(bbl + (size_t)(fq * 64 + n) * 8);                       \
      _Pragma("unroll")                                                               \
      for (int mt = 0; mt < 4; ++mt) {                                                \
        acc[mt][nt] = __builtin_amdgcn_mfma_f32_16x16x32_bf16(ah[mt].s, bh.s, acc[mt][nt], 0, 0, 0); \
        acc[mt][nt] = __builtin_amdgcn_mfma_f32_16x16x32_bf16(ah[mt].s, bl.s, acc[mt][nt], 0, 0, 0); \
        acc[mt][nt] = __builtin_amdgcn_mfma_f32_16x16x32_bf16(al[mt].s, bh.s, acc[mt][nt], 0, 0, 0); \
      }                                                                               \
    }                                                                                 \
  }

  STAGE(0);

  for (int it = 0; it < NIT - 1; ++it) {
    STAGE(it + 1);                      // next tile's loads fly across this compute
    WAITCUR();                          // current tile landed (FIFO per-wave count)
    __builtin_amdgcn_s_barrier();
    __builtin_amdgcn_sched_barrier(0);
    __builtin_amdgcn_s_setprio(1);
    COMPUTE_TILE(it);
    __builtin_amdgcn_s_setprio(0);
    __builtin_amdgcn_sched_barrier(0);
    asm volatile("s_waitcnt lgkmcnt(0)" ::: "memory");
    __builtin_amdgcn_s_barrier();       // safe to overwrite buf it&1 next iter
  }
  asm volatile("s_waitcnt vmcnt(0)" ::: "memory");
  __builtin_amdgcn_s_barrier();
  __builtin_amdgcn_sched_barrier(0);
  __builtin_amdgcn_s_setprio(1);
  COMPUTE_TILE(NIT - 1);
  __builtin_amdgcn_s_setprio(0);
#undef COMPUTE_TILE
#undef WAITCUR
#undef STAGE

  // ---- partial stores (+bias on kz 0) ----
  float* part = logits + (size_t)kz * ((size_t)Hn * Bn * Cn);
#pragma unroll
  for (int nt = 0; nt < 2; ++nt) {
    const int col = n0 + wn + nt * 16 + fl;
    if (col >= Cn) continue;
    const float bv = (kz == 0) ? bias[(size_t)h * Cn + col] : 0.f;
#pragma unroll
    for (int mt = 0; mt < 4; ++mt) {
      const int rbase = m0 + wm + mt * 16 + fq * 4;
#pragma unroll
      for (int r = 0; r < 4; ++r)
        part[((size_t)h * Bn + rbase + r) * Cn + col] = acc[mt][nt][r] + bv;
    }
  }
}

// ============ stats_k: one wave per (h,b) row — max + sum(exp) ============
__global__ __launch_bounds__(64) void stats_k(
    const float* __restrict__ logits, float* __restrict__ msA,
    float* __restrict__ ssA, u32* __restrict__ ticket)
{
  const int id = blockIdx.x;            // h*Bn + b
  const int lane = threadIdx.x;
  if (id == 0 && lane == 0) *ticket = 0;   // reset for pick_k's last-block gate
  const size_t S = (size_t)Hn * Bn * Cn;
  const float* p = logits + (size_t)id * Cn;

  float vv[16];
#pragma unroll
  for (int i = 0; i < 4; ++i) {
    const int c4 = i * 256 + lane * 4;
    if (c4 + 3 < Cn) {
      const float4 v0 = *(const float4*)(p + c4);
      const float4 v1 = *(const float4*)(p + S + c4);
      vv[4 * i + 0] = v0.x + v1.x;
      vv[4 * i + 1] = v0.y + v1.y;
      vv[4 * i + 2] = v0.z + v1.z;
      vv[4 * i + 3] = v0.w + v1.w;
    } else {
#pragma unroll
      for (int j = 0; j < 4; ++j) {
        const int c = c4 + j;
        vv[4 * i + j] = (c < Cn) ? p[c] + p[S + c] : -3.4e38f;
      }
    }
  }
  float m = -3.4e38f;
#pragma unroll
  for (int i = 0; i < 16; ++i) m = fmaxf(m, vv[i]);
#pragma unroll
  for (int off = 32; off >= 1; off >>= 1) m = fmaxf(m, __shfl_xor(m, off));
  float s = 0.f;
#pragma unroll
  for (int i = 0; i < 16; ++i) s += (vv[i] > -3.0e38f) ? expf(vv[i] - m) : 0.f;
#pragma unroll
  for (int off = 32; off >= 1; off >>= 1) s += __shfl_xor(s, off);
  if (lane == 0) { msA[id] = m; ssA[id] = s; }
}

// ============ pick_k: route + gather + CE; last block reduces scalars ============
__global__ __launch_bounds__(256) void pick_k(
    const float* __restrict__ logits, const float* __restrict__ msA,
    const float* __restrict__ ssA, const int* __restrict__ y,
    float* __restrict__ out, float* __restrict__ out_exit,
    float* __restrict__ loss_b, float* __restrict__ corr_b,
    u32* __restrict__ ticket, float* __restrict__ scalars)
{
  const int b = blockIdx.x, tid = threadIdx.x;
  const int lane = tid & 63, w = tid >> 6;
  const size_t S = (size_t)Hn * Bn * Cn;

  int first = -1, best = 0;
  float bestc = -3.4e38f;
#pragma unroll
  for (int h = 0; h < Hn; ++h) {
    const float c = 1.0f / ssA[h * Bn + b];
    if (first < 0 && c >= TAUv) first = h;
    if (c > bestc) { bestc = c; best = h; }
  }
  const int ex = (first >= 0) ? first : best;
  const float* p = logits + ((size_t)ex * Bn + b) * Cn;

  const int c4 = tid * 4;
  float vv[4] = {-3.4e38f, -3.4e38f, -3.4e38f, -3.4e38f};
  if (c4 + 3 < Cn) {
    const float4 v0 = *(const float4*)(p + c4);
    const float4 v1 = *(const float4*)(p + S + c4);
    vv[0] = v0.x + v1.x;
    vv[1] = v0.y + v1.y;
    vv[2] = v0.z + v1.z;
    vv[3] = v0.w + v1.w;
  }
  float vm = -3.4e38f; int im = 1 << 30;
#pragma unroll
  for (int j = 0; j < 4; ++j) {
    const int c = c4 + j;
    if (c < Cn) {
      out[(size_t)b * Cn + c] = vv[j];
      if (vv[j] > vm) { vm = vv[j]; im = c; }
    }
  }
#pragma unroll
  for (int off = 32; off >= 1; off >>= 1) {
    const float ov = __shfl_xor(vm, off);
    const int   oi = __shfl_xor(im, off);
    if (ov > vm || (ov == vm && oi < im)) { vm = ov; im = oi; }
  }
  __shared__ float rm[4]; __shared__ int ri[4];
  __shared__ u32 tk;
  if (lane == 0) { rm[w] = vm; ri[w] = im; }
  __syncthreads();
  if (tid == 0) {
    float bm = rm[0]; int bi = ri[0];
    for (int q = 1; q < 4; ++q)
      if (rm[q] > bm || (rm[q] == bm && ri[q] < bi)) { bm = rm[q]; bi = ri[q]; }
    const int yt = y[b];
    const float ryt = p[yt] + p[S + yt];
    const float lp = ryt - msA[ex * Bn + b] - logf(ssA[ex * Bn + b]);
    out_exit[b] = (float)ex;
    loss_b[b] = -lp;
    corr_b[b] = (bi == yt) ? 1.f : 0.f;
    __threadfence();
    tk = atomicAdd(ticket, 1u);
  }
  __syncthreads();

  if (tk == (u32)(Bn - 1)) {
    __threadfence();
    float l = loss_b[tid] + loss_b[tid + 256];
    float c = corr_b[tid] + corr_b[tid + 256];
#pragma unroll
    for (int off = 32; off >= 1; off >>= 1) {
      l += __shfl_xor(l, off);
      c += __shfl_xor(c, off);
    }
    __shared__ float sl[4], sc[4];
    if (lane == 0) { sl[w] = l; sc[w] = c; }
    __syncthreads();
    if (tid == 0) {
      scalars[0] = (sl[0] + sl[1] + sl[2] + sl[3]) * (1.0f / (float)Bn);
      scalars[1] = (sc[0] + sc[1] + sc[2] + sc[3]) * (1.0f / (float)Bn);
    }
  }
}

extern "C" void kernel_launch(void* const* d_in, const int* in_sizes, int n_in,
                              void* d_out, int out_size, void* d_ws, size_t ws_size,
                              hipStream_t stream) {
  const float* feats = (const float*)d_in[0];   // [H,B,D] fp32
  const float* W     = (const float*)d_in[1];   // [H,D,C] fp32
  const float* bias  = (const float*)d_in[2];   // [H,C]
  const int*   y     = (const int*)d_in[3];     // [B]
  float* out = (float*)d_out;                   // [B*C | B | 1 | 1]

  // ws: logits partials (24,576,000 B) + loss/corr/stats/ticket + Bh/Bl (25.2 MB each)
  float* logits = (float*)d_ws;
  float* loss_b = logits + (size_t)KSPLIT * Hn * Bn * Cn;
  float* corr_b = loss_b + Bn;
  float* msA    = corr_b + Bn;
  float* ssA    = msA + Hn * Bn;
  u32*   ticket = (u32*)(ssA + Hn * Bn);
  u16*   BhG    = (u16*)(ticket + 64);          // align to 256B
  u16*   BlG    = BhG + (size_t)Hn * NKT * 4 * Cpad * 8;
  float* out_exit    = out + (size_t)Bn * Cn;
  float* out_scalars = out + (size_t)Bn * Cn + Bn;

  convW_k<<<dim3(NKT, 8, Hn), 256, 0, stream>>>(W, BhG, BlG);
  gemm_k<<<dim3(768, 1, 1), 256, 0, stream>>>(feats, BhG, BlG, bias, logits);
  stats_k<<<Hn * Bn, 64, 0, stream>>>(logits, msA, ssA, ticket);
  pick_k<<<Bn, 256, 0, stream>>>(logits, msA, ssA, y, out, out_exit,
                                 loss_b, corr_b, ticket, out_scalars);
}

// Round 9
// 169.780 us; speedup vs baseline: 2.6611x; 1.1400x over previous
//
#include <hip/hip_runtime.h>
#include <hip/hip_bf16.h>
#include <math.h>

#define Hn 6
#define Bn 512
#define Dn 2048
#define Cn 1000
#define Cpad 1024
#define TAUv 0.5f
#define KSPLIT 2
#define KPER (Dn / KSPLIT)   // 1024 k per kz slice
#define NIT (KPER / 32)      // 32 k-iters per block
#define NKT (Dn / 32)        // 64 ktiles total

typedef unsigned int u32;
typedef unsigned short u16;
typedef __attribute__((ext_vector_type(8))) short short8;
typedef __attribute__((ext_vector_type(4))) float f32x4;

union FragU { u32 d[4]; short8 s; };

// pack two fp32 -> one dword of bf16 (RNE, f0 in low half; lowers to v_cvt_pk_bf16_f32)
__device__ __forceinline__ u32 cvt_pk2(float f0, float f1) {
  union { __hip_bfloat162 h; u32 u; } cv;
  cv.h = __float22bfloat162_rn(make_float2(f0, f1));
  return cv.u;
}

// 8 fp32 -> hi/lo 16B chunks (RNE both; bit-identical to the 0.03125 pipeline)
__device__ __forceinline__ void pack8(const float* rr, uint4& hv, uint4& lv) {
  u32 hd[4], ld[4];
  float r[8];
#pragma unroll
  for (int i = 0; i < 4; ++i) {
    const u32 d = cvt_pk2(rr[2 * i], rr[2 * i + 1]);
    hd[i] = d;
    r[2 * i]     = rr[2 * i]     - __uint_as_float(d << 16);
    r[2 * i + 1] = rr[2 * i + 1] - __uint_as_float(d & 0xffff0000u);
  }
#pragma unroll
  for (int i = 0; i < 4; ++i) ld[i] = cvt_pk2(r[2 * i], r[2 * i + 1]);
  hv = make_uint4(hd[0], hd[1], hd[2], hd[3]);
  lv = make_uint4(ld[0], ld[1], ld[2], ld[3]);
}

// async global->LDS DMA, 16 B/lane; LDS dest = wave-uniform base + lane*16 (linear!)
__device__ __forceinline__ void dma16(const void* g, void* l) {
  __builtin_amdgcn_global_load_lds(
      (const __attribute__((address_space(1))) u32*)g,
      (__attribute__((address_space(3))) u32*)l, 16, 0, 0);
}

// ============ conv_k (R0 verbatim): fp32 -> k-tiled split-bf16 ============
// yy < 4 : feats [H][B][D] -> Ah/Al [H][64][4][512][8]
// yy >= 4: W [H][D][C] -> transposed Bh/Bl [H][64][4][1024][8] (zeros past Cn)
__global__ __launch_bounds__(256) void conv_k(
    const float* __restrict__ feats, const float* __restrict__ W,
    u16* __restrict__ Ah, u16* __restrict__ Al,
    u16* __restrict__ Bh, u16* __restrict__ Bl)
{
  __shared__ float smem[128 * 33];   // aconv: [128][33]; bconv: [32][129]
  const int t   = blockIdx.x;        // ktile 0..63
  const int yy  = blockIdx.y;        // 0..11
  const int h   = blockIdx.z;
  const int tid = threadIdx.x;

  if (yy < 4) {
    const int r0 = yy * 128;
#pragma unroll
    for (int i = 0; i < 4; ++i) {
      const int f = i * 256 + tid;     // 0..1023 float4 tasks
      const int r = f >> 3, q = f & 7;
      const float4 v = *(const float4*)(feats + ((size_t)(h * Bn + r0 + r) * Dn + t * 32 + q * 4));
      smem[r * 33 + q * 4 + 0] = v.x; smem[r * 33 + q * 4 + 1] = v.y;
      smem[r * 33 + q * 4 + 2] = v.z; smem[r * 33 + q * 4 + 3] = v.w;
    }
    __syncthreads();
#pragma unroll
    for (int i = 0; i < 2; ++i) {
      const int j = i * 256 + tid;     // 0..511 chunk tasks
      const int c = j >> 7, r = j & 127;
      float rr[8];
#pragma unroll
      for (int e = 0; e < 8; ++e) rr[e] = smem[r * 33 + c * 8 + e];
      uint4 hv, lv;
      pack8(rr, hv, lv);
      const size_t o = (((size_t)(h * 64 + t) * 4 + c) * 512 + r0 + r);
      ((uint4*)Ah)[o] = hv;
      ((uint4*)Al)[o] = lv;
    }
  } else {
    const int n0 = (yy - 4) * 128;
#pragma unroll
    for (int i = 0; i < 4; ++i) {
      const int f = i * 256 + tid;     // 0..1023
      const int k = f >> 5, q = f & 31;
      const int n = n0 + q * 4;
      const float* src = W + ((size_t)h * Dn + t * 32 + k) * Cn;
      float4 v = make_float4(0.f, 0.f, 0.f, 0.f);
      if (n + 3 < Cn) {
        v = *(const float4*)(src + n);
      } else {
        if (n + 0 < Cn) v.x = src[n + 0];
        if (n + 1 < Cn) v.y = src[n + 1];
        if (n + 2 < Cn) v.z = src[n + 2];
        if (n + 3 < Cn) v.w = src[n + 3];
      }
      smem[k * 129 + q * 4 + 0] = v.x; smem[k * 129 + q * 4 + 1] = v.y;
      smem[k * 129 + q * 4 + 2] = v.z; smem[k * 129 + q * 4 + 3] = v.w;
    }
    __syncthreads();
#pragma unroll
    for (int i = 0; i < 2; ++i) {
      const int j = i * 256 + tid;     // 0..511
      const int c = j >> 7, n = j & 127;
      float rr[8];
#pragma unroll
      for (int e = 0; e < 8; ++e) rr[e] = smem[(c * 8 + e) * 129 + n];
      uint4 hv, lv;
      pack8(rr, hv, lv);
      const size_t o = (((size_t)(h * 64 + t) * 4 + c) * 1024 + n0 + n);
      ((uint4*)Bh)[o] = hv;
      ((uint4*)Bl)[o] = lv;
    }
  }
}

// ============ split-bf16 MFMA GEMM: fully prepacked, T4 double-buffered ============
// 128x128 tile, BK=32, KSPLIT=2. LDS 2 x (Ah 8K | Al 8K | Bh 8K | Bl 8K) = 64 KB,
// 2 blocks/CU, 384-block flat grid, XCD-chunked swizzle (384 = 8 x 48).
// Per iter: wave w stages matrix w (8 x 1KB coalesced dma16); counted vmcnt(8)
// keeps next tile's loads in flight across compute; 48 MFMA per barrier pair.
// R0 structure (50us, VALU 14%, 0 bank conflicts) + dbuf/T4/setprio upgrades.
__global__ __launch_bounds__(256, 2) void gemm_k(
    const u16* __restrict__ AhG, const u16* __restrict__ AlG,
    const u16* __restrict__ BhG, const u16* __restrict__ BlG,
    const float* __restrict__ bias, float* __restrict__ logits)
{
  const int bid = blockIdx.x;
  const int wg = (bid & 7) * 48 + (bid >> 3);   // XCD-chunked: 48 consecutive per XCD
  const int n0 = (wg & 7) * 128;
  const int m0 = ((wg >> 3) & 3) * 128;
  const int z  = wg >> 5;                        // 0..11
  const int h  = z >> 1;
  const int kz = z & 1;
  const int t = threadIdx.x, lane = t & 63, w = t >> 6;

  __shared__ __align__(16) char lds[2][32768];   // per buf: Ah|Al|Bh|Bl, 8 KB each

  // wave w stages matrix w; k-tiled layout -> each dma16 is a 1KB coalesced burst
  const u16* gmat = (w == 0) ? AhG : (w == 1) ? AlG : (w == 2) ? BhG : BlG;
  const int  R    = (w < 2) ? 512 : 1024;
  const int  row0 = (w < 2) ? m0 : n0;
  const uint4* g0 = (const uint4*)gmat
                  + ((size_t)(h * 64 + kz * NIT) * 4) * R + row0 + lane;
  const int dstw = w * 8192 + lane * 16;

  const int fl = lane & 15, fq = lane >> 4;
  const int wm = (w & 1) * 64, wn = (w >> 1) * 64;

  f32x4 acc[4][4];
#pragma unroll
  for (int i = 0; i < 4; ++i)
#pragma unroll
    for (int j = 0; j < 4; ++j) acc[i][j] = (f32x4){0.f, 0.f, 0.f, 0.f};

#define STAGE(TILE)                                                                   \
  {                                                                                   \
    char* sb = &lds[(TILE) & 1][0];                                                   \
    const uint4* g = g0 + (size_t)(TILE) * 4 * R;                                     \
    _Pragma("unroll")                                                                 \
    for (int i = 0; i < 8; ++i)                                                       \
      dma16(g + (size_t)(i >> 1) * R + (i & 1) * 64, sb + dstw + i * 1024);           \
  }

#define COMPUTE_TILE(IT)                                                              \
  {                                                                                   \
    const char* bb = &lds[(IT) & 1][0];                                               \
    FragU ah[4], al[4];                                                               \
    _Pragma("unroll")                                                                 \
    for (int mt = 0; mt < 4; ++mt) {                                                  \
      const int r = wm + mt * 16 + fl;                                                \
      ah[mt].s = *(const short8*)(bb + (fq * 128 + r) * 16);                          \
      al[mt].s = *(const short8*)(bb + 8192 + (fq * 128 + r) * 16);                   \
    }                                                                                 \
    _Pragma("unroll")                                                                 \
    for (int nt = 0; nt < 4; ++nt) {                                                  \
      const int n = wn + nt * 16 + fl;                                                \
      FragU bh, bl;                                                                   \
      bh.s = *(const short8*)(bb + 16384 + (fq * 128 + n) * 16);                      \
      bl.s = *(const short8*)(bb + 24576 + (fq * 128 + n) * 16);                      \
      _Pragma("unroll")                                                               \
      for (int mt = 0; mt < 4; ++mt) {                                                \
        acc[mt][nt] = __builtin_amdgcn_mfma_f32_16x16x32_bf16(ah[mt].s, bh.s, acc[mt][nt], 0, 0, 0); \
        acc[mt][nt] = __builtin_amdgcn_mfma_f32_16x16x32_bf16(ah[mt].s, bl.s, acc[mt][nt], 0, 0, 0); \
        acc[mt][nt] = __builtin_amdgcn_mfma_f32_16x16x32_bf16(al[mt].s, bh.s, acc[mt][nt], 0, 0, 0); \
      }                                                                               \
    }                                                                                 \
  }

  STAGE(0);

  for (int it = 0; it < NIT - 1; ++it) {
    STAGE(it + 1);                                      // 8 loads/wave -> buf (it+1)&1
    asm volatile("s_waitcnt vmcnt(8)" ::: "memory");    // tile it landed; it+1 in flight
    __builtin_amdgcn_s_barrier();
    __builtin_amdgcn_sched_barrier(0);
    __builtin_amdgcn_s_setprio(1);
    COMPUTE_TILE(it);
    __builtin_amdgcn_s_setprio(0);
    __builtin_amdgcn_sched_barrier(0);
    asm volatile("s_waitcnt lgkmcnt(0)" ::: "memory");  // LDS reads of buf it&1 done
    __builtin_amdgcn_s_barrier();                       // safe to overwrite next iter
  }
  asm volatile("s_waitcnt vmcnt(0)" ::: "memory");
  __builtin_amdgcn_s_barrier();
  __builtin_amdgcn_sched_barrier(0);
  __builtin_amdgcn_s_setprio(1);
  COMPUTE_TILE(NIT - 1);
  __builtin_amdgcn_s_setprio(0);
#undef COMPUTE_TILE
#undef STAGE

  // ---- partial stores (+bias on kz 0), proven mapping ----
  float* part = logits + (size_t)kz * ((size_t)Hn * Bn * Cn);
#pragma unroll
  for (int nt = 0; nt < 4; ++nt) {
    const int col = n0 + wn + nt * 16 + fl;
    if (col >= Cn) continue;
    const float bv = (kz == 0) ? bias[(size_t)h * Cn + col] : 0.f;
#pragma unroll
    for (int mt = 0; mt < 4; ++mt) {
      const int rbase = m0 + wm + mt * 16 + fq * 4;
#pragma unroll
      for (int r = 0; r < 4; ++r)
        part[((size_t)h * Bn + rbase + r) * Cn + col] = acc[mt][nt][r] + bv;
    }
  }
}

// ============ fused conf + route + gather + CE (R5 version, 2-term partials) ============
__global__ __launch_bounds__(256) void confpick_k(
    const float* __restrict__ logits, const int* __restrict__ y,
    float* __restrict__ out, float* __restrict__ out_exit,
    float* __restrict__ loss_b, float* __restrict__ corr_b)
{
  const int b = blockIdx.x, tid = threadIdx.x;
  const int lane = tid & 63, w = tid >> 6;
  const size_t S = (size_t)Hn * Bn * Cn;
  __shared__ float ms[Hn], ss[Hn];

  for (int h = w; h < Hn; h += 4) {
    const float* p = logits + ((size_t)h * Bn + b) * Cn;
    float vv[16];
#pragma unroll
    for (int i = 0; i < 4; ++i) {
      const int c4 = i * 256 + lane * 4;
      if (c4 + 3 < Cn) {
        const float4 v0 = *(const float4*)(p + c4);
        const float4 v1 = *(const float4*)(p + S + c4);
        vv[4 * i + 0] = v0.x + v1.x;
        vv[4 * i + 1] = v0.y + v1.y;
        vv[4 * i + 2] = v0.z + v1.z;
        vv[4 * i + 3] = v0.w + v1.w;
      } else {
#pragma unroll
        for (int j = 0; j < 4; ++j) {
          const int c = c4 + j;
          vv[4 * i + j] = (c < Cn) ? p[c] + p[S + c] : -3.4e38f;
        }
      }
    }
    float m = -3.4e38f;
#pragma unroll
    for (int i = 0; i < 16; ++i) m = fmaxf(m, vv[i]);
#pragma unroll
    for (int off = 32; off >= 1; off >>= 1) m = fmaxf(m, __shfl_xor(m, off));
    float s = 0.f;
#pragma unroll
    for (int i = 0; i < 16; ++i) s += (vv[i] > -3.0e38f) ? expf(vv[i] - m) : 0.f;
#pragma unroll
    for (int off = 32; off >= 1; off >>= 1) s += __shfl_xor(s, off);
    if (lane == 0) { ms[h] = m; ss[h] = s; }
  }
  __syncthreads();

  int first = -1, best = 0;
  float bestc = -3.4e38f;
#pragma unroll
  for (int h = 0; h < Hn; ++h) {
    const float c = 1.0f / ss[h];                   // max softmax prob
    if (first < 0 && c >= TAUv) first = h;
    if (c > bestc) { bestc = c; best = h; }         // strict > keeps first occurrence
  }
  const int ex = (first >= 0) ? first : best;
  const float* p = logits + ((size_t)ex * Bn + b) * Cn;

  const int c4 = tid * 4;
  float vv[4] = {-3.4e38f, -3.4e38f, -3.4e38f, -3.4e38f};
  if (c4 + 3 < Cn) {
    const float4 v0 = *(const float4*)(p + c4);
    const float4 v1 = *(const float4*)(p + S + c4);
    vv[0] = v0.x + v1.x;
    vv[1] = v0.y + v1.y;
    vv[2] = v0.z + v1.z;
    vv[3] = v0.w + v1.w;
  }
  float vm = -3.4e38f; int im = 1 << 30;
#pragma unroll
  for (int j = 0; j < 4; ++j) {
    const int c = c4 + j;
    if (c < Cn) {
      out[(size_t)b * Cn + c] = vv[j];
      if (vv[j] > vm) { vm = vv[j]; im = c; }       // ascending c keeps first max
    }
  }
#pragma unroll
  for (int off = 32; off >= 1; off >>= 1) {
    const float ov = __shfl_xor(vm, off);
    const int   oi = __shfl_xor(im, off);
    if (ov > vm || (ov == vm && oi < im)) { vm = ov; im = oi; }
  }
  __shared__ float rm[4]; __shared__ int ri[4];
  if (lane == 0) { rm[w] = vm; ri[w] = im; }
  __syncthreads();
  if (tid == 0) {
    float bm = rm[0]; int bi = ri[0];
    for (int q = 1; q < 4; ++q)
      if (rm[q] > bm || (rm[q] == bm && ri[q] < bi)) { bm = rm[q]; bi = ri[q]; }
    const int yt = y[b];
    const float ryt = p[yt] + p[S + yt];
    const float lp = ryt - ms[ex] - logf(ss[ex]);
    out_exit[b] = (float)ex;
    loss_b[b] = -lp;
    corr_b[b] = (bi == yt) ? 1.f : 0.f;
  }
}

// ============ deterministic 1-block mean reduce: 512 -> 2 scalars ============
__global__ __launch_bounds__(256) void reduce_k(
    const float* __restrict__ loss_b, const float* __restrict__ corr_b,
    float* __restrict__ scalars)
{
  const int t = threadIdx.x, lane = t & 63, w = t >> 6;
  float l = loss_b[t] + loss_b[t + 256];
  float c = corr_b[t] + corr_b[t + 256];
#pragma unroll
  for (int off = 32; off >= 1; off >>= 1) {
    l += __shfl_xor(l, off);
    c += __shfl_xor(c, off);
  }
  __shared__ float sl[4], sc[4];
  if (lane == 0) { sl[w] = l; sc[w] = c; }
  __syncthreads();
  if (t == 0) {
    scalars[0] = (sl[0] + sl[1] + sl[2] + sl[3]) * (1.0f / (float)Bn);
    scalars[1] = (sc[0] + sc[1] + sc[2] + sc[3]) * (1.0f / (float)Bn);
  }
}

extern "C" void kernel_launch(void* const* d_in, const int* in_sizes, int n_in,
                              void* d_out, int out_size, void* d_ws, size_t ws_size,
                              hipStream_t stream) {
  const float* feats = (const float*)d_in[0];   // [H,B,D] fp32
  const float* W     = (const float*)d_in[1];   // [H,D,C] fp32
  const float* bias  = (const float*)d_in[2];   // [H,C]
  const int*   y     = (const int*)d_in[3];     // [B]
  float* out = (float*)d_out;                   // [B*C | B | 1 | 1]

  // ws: logits partials (24,576,000 B) + loss/corr + Ah/Al (12.6 MB ea) + Bh/Bl (25.2 MB ea)
  float* logits = (float*)d_ws;
  float* loss_b = logits + (size_t)KSPLIT * Hn * Bn * Cn;
  float* corr_b = loss_b + Bn;
  u16*   AhG    = (u16*)(corr_b + Bn + 64);     // pad to 16B alignment
  u16*   AlG    = AhG + (size_t)Hn * NKT * 4 * 512 * 8;
  u16*   BhG    = AlG + (size_t)Hn * NKT * 4 * 512 * 8;
  u16*   BlG    = BhG + (size_t)Hn * NKT * 4 * 1024 * 8;
  float* out_exit    = out + (size_t)Bn * Cn;
  float* out_scalars = out + (size_t)Bn * Cn + Bn;

  conv_k<<<dim3(NKT, 12, Hn), 256, 0, stream>>>(feats, W, AhG, AlG, BhG, BlG);
  gemm_k<<<dim3(384, 1, 1), 256, 0, stream>>>(AhG, AlG, BhG, BlG, bias, logits);
  confpick_k<<<Bn, 256, 0, stream>>>(logits, y, out, out_exit, loss_b, corr_b);
  reduce_k<<<1, 256, 0, stream>>>(loss_b, corr_b, out_scalars);
}

// Round 10
// 167.487 us; speedup vs baseline: 2.6975x; 1.0137x over previous
//
#include <hip/hip_runtime.h>
#include <hip/hip_bf16.h>
#include <math.h>

#define Hn 6
#define Bn 512
#define Dn 2048
#define Cn 1000
#define Cpad 1024
#define TAUv 0.5f
#define KSPLIT 2
#define KPER (Dn / KSPLIT)   // 1024 k per kz slice
#define NIT (KPER / 32)      // 32 k-iters per block
#define NKT (Dn / 32)        // 64 ktiles total

typedef unsigned int u32;
typedef unsigned short u16;
typedef __attribute__((ext_vector_type(8))) short short8;
typedef __attribute__((ext_vector_type(4))) float f32x4;

union FragU { u32 d[4]; short8 s; };

// pack two fp32 -> one dword of bf16 (RNE, f0 in low half; lowers to v_cvt_pk_bf16_f32)
__device__ __forceinline__ u32 cvt_pk2(float f0, float f1) {
  union { __hip_bfloat162 h; u32 u; } cv;
  cv.h = __float22bfloat162_rn(make_float2(f0, f1));
  return cv.u;
}

// 8 fp32 -> hi/lo 16B chunks (RNE both; bit-identical to the 0.03125 pipeline)
__device__ __forceinline__ void pack8(const float* rr, uint4& hv, uint4& lv) {
  u32 hd[4], ld[4];
  float r[8];
#pragma unroll
  for (int i = 0; i < 4; ++i) {
    const u32 d = cvt_pk2(rr[2 * i], rr[2 * i + 1]);
    hd[i] = d;
    r[2 * i]     = rr[2 * i]     - __uint_as_float(d << 16);
    r[2 * i + 1] = rr[2 * i + 1] - __uint_as_float(d & 0xffff0000u);
  }
#pragma unroll
  for (int i = 0; i < 4; ++i) ld[i] = cvt_pk2(r[2 * i], r[2 * i + 1]);
  hv = make_uint4(hd[0], hd[1], hd[2], hd[3]);
  lv = make_uint4(ld[0], ld[1], ld[2], ld[3]);
}

// async global->LDS DMA, 16 B/lane; LDS dest = wave-uniform base + lane*16 (linear!)
__device__ __forceinline__ void dma16(const void* g, void* l) {
  __builtin_amdgcn_global_load_lds(
      (const __attribute__((address_space(1))) u32*)g,
      (__attribute__((address_space(3))) u32*)l, 16, 0, 0);
}

// ============ conv_k (R0 verbatim): fp32 -> k-tiled split-bf16 ============
// yy < 4 : feats [H][B][D] -> Ah/Al [H][64][4][512][8]
// yy >= 4: W [H][D][C] -> transposed Bh/Bl [H][64][4][1024][8] (zeros past Cn)
__global__ __launch_bounds__(256) void conv_k(
    const float* __restrict__ feats, const float* __restrict__ W,
    u16* __restrict__ Ah, u16* __restrict__ Al,
    u16* __restrict__ Bh, u16* __restrict__ Bl)
{
  __shared__ float smem[128 * 33];   // aconv: [128][33]; bconv: [32][129]
  const int t   = blockIdx.x;        // ktile 0..63
  const int yy  = blockIdx.y;        // 0..11
  const int h   = blockIdx.z;
  const int tid = threadIdx.x;

  if (yy < 4) {
    const int r0 = yy * 128;
#pragma unroll
    for (int i = 0; i < 4; ++i) {
      const int f = i * 256 + tid;     // 0..1023 float4 tasks
      const int r = f >> 3, q = f & 7;
      const float4 v = *(const float4*)(feats + ((size_t)(h * Bn + r0 + r) * Dn + t * 32 + q * 4));
      smem[r * 33 + q * 4 + 0] = v.x; smem[r * 33 + q * 4 + 1] = v.y;
      smem[r * 33 + q * 4 + 2] = v.z; smem[r * 33 + q * 4 + 3] = v.w;
    }
    __syncthreads();
#pragma unroll
    for (int i = 0; i < 2; ++i) {
      const int j = i * 256 + tid;     // 0..511 chunk tasks
      const int c = j >> 7, r = j & 127;
      float rr[8];
#pragma unroll
      for (int e = 0; e < 8; ++e) rr[e] = smem[r * 33 + c * 8 + e];
      uint4 hv, lv;
      pack8(rr, hv, lv);
      const size_t o = (((size_t)(h * 64 + t) * 4 + c) * 512 + r0 + r);
      ((uint4*)Ah)[o] = hv;
      ((uint4*)Al)[o] = lv;
    }
  } else {
    const int n0 = (yy - 4) * 128;
#pragma unroll
    for (int i = 0; i < 4; ++i) {
      const int f = i * 256 + tid;     // 0..1023
      const int k = f >> 5, q = f & 31;
      const int n = n0 + q * 4;
      const float* src = W + ((size_t)h * Dn + t * 32 + k) * Cn;
      float4 v = make_float4(0.f, 0.f, 0.f, 0.f);
      if (n + 3 < Cn) {
        v = *(const float4*)(src + n);
      } else {
        if (n + 0 < Cn) v.x = src[n + 0];
        if (n + 1 < Cn) v.y = src[n + 1];
        if (n + 2 < Cn) v.z = src[n + 2];
        if (n + 3 < Cn) v.w = src[n + 3];
      }
      smem[k * 129 + q * 4 + 0] = v.x; smem[k * 129 + q * 4 + 1] = v.y;
      smem[k * 129 + q * 4 + 2] = v.z; smem[k * 129 + q * 4 + 3] = v.w;
    }
    __syncthreads();
#pragma unroll
    for (int i = 0; i < 2; ++i) {
      const int j = i * 256 + tid;     // 0..511
      const int c = j >> 7, n = j & 127;
      float rr[8];
#pragma unroll
      for (int e = 0; e < 8; ++e) rr[e] = smem[(c * 8 + e) * 129 + n];
      uint4 hv, lv;
      pack8(rr, hv, lv);
      const size_t o = (((size_t)(h * 64 + t) * 4 + c) * 1024 + n0 + n);
      ((uint4*)Bh)[o] = hv;
      ((uint4*)Bl)[o] = lv;
    }
  }
}

// ============ split-bf16 MFMA GEMM: prepacked, T4 dbuf, balanced 768-grid ============
// Tile 128(M)x64(N), BK=32, KSPLIT=2. LDS 2 x (Ah 8K | Al 8K | Bh 4K | Bl 4K) = 48 KB
// -> 3 blocks/CU; grid 768 = 256 CU x 3 resident: perfect balance, no tail rounds.
// Wave w stages matrix w (A-waves 8 x 1KB dma16/iter, B-waves 4); counted vmcnt
// (A:8, B:4) keeps next tile's loads in flight across compute; 24 MFMA + 12 b128
// per wave-iter; zero bank conflicts (measured 0 in R9's identical read pattern).
__global__ __launch_bounds__(256, 3) void gemm_k(
    const u16* __restrict__ AhG, const u16* __restrict__ AlG,
    const u16* __restrict__ BhG, const u16* __restrict__ BlG,
    const float* __restrict__ bias, float* __restrict__ logits)
{
  const int bid = blockIdx.x;
  const int wg = (bid & 7) * 96 + (bid >> 3);   // XCD-chunked: 96 consecutive per XCD
  const int n0 = (wg & 15) * 64;
  const int m0 = ((wg >> 4) & 3) * 128;
  const int z  = wg >> 6;                        // 0..11
  const int h  = z >> 1;
  const int kz = z & 1;
  const int t = threadIdx.x, lane = t & 63, w = t >> 6;

  __shared__ __align__(16) char lds[2][24576];   // per buf: Ah 8K | Al 8K | Bh 4K | Bl 4K

  // wave w stages matrix w; k-tiled layout -> each dma16 is a 1KB coalesced burst
  const u16* gmat = (w == 0) ? AhG : (w == 1) ? AlG : (w == 2) ? BhG : BlG;
  const int  R    = (w < 2) ? 512 : 1024;
  const int  row0 = (w < 2) ? m0 : n0;
  const uint4* g0 = (const uint4*)gmat
                  + ((size_t)(h * 64 + kz * NIT) * 4) * R + row0 + lane;
  const int dstw = (w < 2) ? w * 8192 : 16384 + (w - 2) * 4096;

  const int fl = lane & 15, fq = lane >> 4;
  const int wm = (w & 1) * 64, wn = (w >> 1) * 32;

  f32x4 acc[4][2];
#pragma unroll
  for (int i = 0; i < 4; ++i)
#pragma unroll
    for (int j = 0; j < 2; ++j) acc[i][j] = (f32x4){0.f, 0.f, 0.f, 0.f};

#define STAGE(TILE)                                                                   \
  {                                                                                   \
    char* sb = &lds[(TILE) & 1][0];                                                   \
    const uint4* g = g0 + (size_t)(TILE) * 4 * R;                                     \
    if (w < 2) {                                                                      \
      _Pragma("unroll")                                                               \
      for (int i = 0; i < 8; ++i)                                                     \
        dma16(g + (size_t)(i >> 1) * R + (i & 1) * 64,                                \
              sb + dstw + lane * 16 + i * 1024);                                      \
    } else {                                                                          \
      _Pragma("unroll")                                                               \
      for (int i = 0; i < 4; ++i)                                                     \
        dma16(g + (size_t)i * R, sb + dstw + lane * 16 + i * 1024);                   \
    }                                                                                 \
  }

#define WAITCUR()                                                                     \
  {                                                                                   \
    if (w < 2) asm volatile("s_waitcnt vmcnt(8)" ::: "memory");                       \
    else       asm volatile("s_waitcnt vmcnt(4)" ::: "memory");                       \
  }

#define COMPUTE_TILE(IT)                                                              \
  {                                                                                   \
    const char* bb = &lds[(IT) & 1][0];                                               \
    FragU ah[4], al[4];                                                               \
    _Pragma("unroll")                                                                 \
    for (int mt = 0; mt < 4; ++mt) {                                                  \
      const int r = wm + mt * 16 + fl;                                                \
      ah[mt].s = *(const short8*)(bb + (fq * 128 + r) * 16);                          \
      al[mt].s = *(const short8*)(bb + 8192 + (fq * 128 + r) * 16);                   \
    }                                                                                 \
    _Pragma("unroll")                                                                 \
    for (int nt = 0; nt < 2; ++nt) {                                                  \
      const int n = wn + nt * 16 + fl;                                                \
      FragU bh, bl;                                                                   \
      bh.s = *(const short8*)(bb + 16384 + (fq * 64 + n) * 16);                       \
      bl.s = *(const short8*)(bb + 20480 + (fq * 64 + n) * 16);                       \
      _Pragma("unroll")                                                               \
      for (int mt = 0; mt < 4; ++mt) {                                                \
        acc[mt][nt] = __builtin_amdgcn_mfma_f32_16x16x32_bf16(ah[mt].s, bh.s, acc[mt][nt], 0, 0, 0); \
        acc[mt][nt] = __builtin_amdgcn_mfma_f32_16x16x32_bf16(ah[mt].s, bl.s, acc[mt][nt], 0, 0, 0); \
        acc[mt][nt] = __builtin_amdgcn_mfma_f32_16x16x32_bf16(al[mt].s, bh.s, acc[mt][nt], 0, 0, 0); \
      }                                                                               \
    }                                                                                 \
  }

  STAGE(0);

  for (int it = 0; it < NIT - 1; ++it) {
    STAGE(it + 1);                                      // next tile -> buf (it+1)&1
    WAITCUR();                                          // tile it landed; it+1 in flight
    __builtin_amdgcn_s_barrier();
    __builtin_amdgcn_sched_barrier(0);
    __builtin_amdgcn_s_setprio(1);
    COMPUTE_TILE(it);
    __builtin_amdgcn_s_setprio(0);
    __builtin_amdgcn_sched_barrier(0);
    asm volatile("s_waitcnt lgkmcnt(0)" ::: "memory");  // LDS reads of buf it&1 done
    __builtin_amdgcn_s_barrier();                       // safe to overwrite next iter
  }
  asm volatile("s_waitcnt vmcnt(0)" ::: "memory");
  __builtin_amdgcn_s_barrier();
  __builtin_amdgcn_sched_barrier(0);
  __builtin_amdgcn_s_setprio(1);
  COMPUTE_TILE(NIT - 1);
  __builtin_amdgcn_s_setprio(0);
#undef COMPUTE_TILE
#undef WAITCUR
#undef STAGE

  // ---- partial stores (+bias on kz 0), proven mapping ----
  float* part = logits + (size_t)kz * ((size_t)Hn * Bn * Cn);
#pragma unroll
  for (int nt = 0; nt < 2; ++nt) {
    const int col = n0 + wn + nt * 16 + fl;
    if (col >= Cn) continue;
    const float bv = (kz == 0) ? bias[(size_t)h * Cn + col] : 0.f;
#pragma unroll
    for (int mt = 0; mt < 4; ++mt) {
      const int rbase = m0 + wm + mt * 16 + fq * 4;
#pragma unroll
      for (int r = 0; r < 4; ++r)
        part[((size_t)h * Bn + rbase + r) * Cn + col] = acc[mt][nt][r] + bv;
    }
  }
}

// ============ fused conf + route + gather + CE (2-term partials) ============
__global__ __launch_bounds__(256) void confpick_k(
    const float* __restrict__ logits, const int* __restrict__ y,
    float* __restrict__ out, float* __restrict__ out_exit,
    float* __restrict__ loss_b, float* __restrict__ corr_b)
{
  const int b = blockIdx.x, tid = threadIdx.x;
  const int lane = tid & 63, w = tid >> 6;
  const size_t S = (size_t)Hn * Bn * Cn;
  __shared__ float ms[Hn], ss[Hn];

  for (int h = w; h < Hn; h += 4) {
    const float* p = logits + ((size_t)h * Bn + b) * Cn;
    float vv[16];
#pragma unroll
    for (int i = 0; i < 4; ++i) {
      const int c4 = i * 256 + lane * 4;
      if (c4 + 3 < Cn) {
        const float4 v0 = *(const float4*)(p + c4);
        const float4 v1 = *(const float4*)(p + S + c4);
        vv[4 * i + 0] = v0.x + v1.x;
        vv[4 * i + 1] = v0.y + v1.y;
        vv[4 * i + 2] = v0.z + v1.z;
        vv[4 * i + 3] = v0.w + v1.w;
      } else {
#pragma unroll
        for (int j = 0; j < 4; ++j) {
          const int c = c4 + j;
          vv[4 * i + j] = (c < Cn) ? p[c] + p[S + c] : -3.4e38f;
        }
      }
    }
    float m = -3.4e38f;
#pragma unroll
    for (int i = 0; i < 16; ++i) m = fmaxf(m, vv[i]);
#pragma unroll
    for (int off = 32; off >= 1; off >>= 1) m = fmaxf(m, __shfl_xor(m, off));
    float s = 0.f;
#pragma unroll
    for (int i = 0; i < 16; ++i) s += (vv[i] > -3.0e38f) ? expf(vv[i] - m) : 0.f;
#pragma unroll
    for (int off = 32; off >= 1; off >>= 1) s += __shfl_xor(s, off);
    if (lane == 0) { ms[h] = m; ss[h] = s; }
  }
  __syncthreads();

  int first = -1, best = 0;
  float bestc = -3.4e38f;
#pragma unroll
  for (int h = 0; h < Hn; ++h) {
    const float c = 1.0f / ss[h];                   // max softmax prob
    if (first < 0 && c >= TAUv) first = h;
    if (c > bestc) { bestc = c; best = h; }         // strict > keeps first occurrence
  }
  const int ex = (first >= 0) ? first : best;
  const float* p = logits + ((size_t)ex * Bn + b) * Cn;

  const int c4 = tid * 4;
  float vv[4] = {-3.4e38f, -3.4e38f, -3.4e38f, -3.4e38f};
  if (c4 + 3 < Cn) {
    const float4 v0 = *(const float4*)(p + c4);
    const float4 v1 = *(const float4*)(p + S + c4);
    vv[0] = v0.x + v1.x;
    vv[1] = v0.y + v1.y;
    vv[2] = v0.z + v1.z;
    vv[3] = v0.w + v1.w;
  }
  float vm = -3.4e38f; int im = 1 << 30;
#pragma unroll
  for (int j = 0; j < 4; ++j) {
    const int c = c4 + j;
    if (c < Cn) {
      out[(size_t)b * Cn + c] = vv[j];
      if (vv[j] > vm) { vm = vv[j]; im = c; }       // ascending c keeps first max
    }
  }
#pragma unroll
  for (int off = 32; off >= 1; off >>= 1) {
    const float ov = __shfl_xor(vm, off);
    const int   oi = __shfl_xor(im, off);
    if (ov > vm || (ov == vm && oi < im)) { vm = ov; im = oi; }
  }
  __shared__ float rm[4]; __shared__ int ri[4];
  if (lane == 0) { rm[w] = vm; ri[w] = im; }
  __syncthreads();
  if (tid == 0) {
    float bm = rm[0]; int bi = ri[0];
    for (int q = 1; q < 4; ++q)
      if (rm[q] > bm || (rm[q] == bm && ri[q] < bi)) { bm = rm[q]; bi = ri[q]; }
    const int yt = y[b];
    const float ryt = p[yt] + p[S + yt];
    const float lp = ryt - ms[ex] - logf(ss[ex]);
    out_exit[b] = (float)ex;
    loss_b[b] = -lp;
    corr_b[b] = (bi == yt) ? 1.f : 0.f;
  }
}

// ============ deterministic 1-block mean reduce: 512 -> 2 scalars ============
__global__ __launch_bounds__(256) void reduce_k(
    const float* __restrict__ loss_b, const float* __restrict__ corr_b,
    float* __restrict__ scalars)
{
  const int t = threadIdx.x, lane = t & 63, w = t >> 6;
  float l = loss_b[t] + loss_b[t + 256];
  float c = corr_b[t] + corr_b[t + 256];
#pragma unroll
  for (int off = 32; off >= 1; off >>= 1) {
    l += __shfl_xor(l, off);
    c += __shfl_xor(c, off);
  }
  __shared__ float sl[4], sc[4];
  if (lane == 0) { sl[w] = l; sc[w] = c; }
  __syncthreads();
  if (t == 0) {
    scalars[0] = (sl[0] + sl[1] + sl[2] + sl[3]) * (1.0f / (float)Bn);
    scalars[1] = (sc[0] + sc[1] + sc[2] + sc[3]) * (1.0f / (float)Bn);
  }
}

extern "C" void kernel_launch(void* const* d_in, const int* in_sizes, int n_in,
                              void* d_out, int out_size, void* d_ws, size_t ws_size,
                              hipStream_t stream) {
  const float* feats = (const float*)d_in[0];   // [H,B,D] fp32
  const float* W     = (const float*)d_in[1];   // [H,D,C] fp32
  const float* bias  = (const float*)d_in[2];   // [H,C]
  const int*   y     = (const int*)d_in[3];     // [B]
  float* out = (float*)d_out;                   // [B*C | B | 1 | 1]

  // ws: logits partials (24,576,000 B) + loss/corr + Ah/Al (12.6 MB ea) + Bh/Bl (25.2 MB ea)
  float* logits = (float*)d_ws;
  float* loss_b = logits + (size_t)KSPLIT * Hn * Bn * Cn;
  float* corr_b = loss_b + Bn;
  u16*   AhG    = (u16*)(corr_b + Bn + 64);     // pad to 16B alignment
  u16*   AlG    = AhG + (size_t)Hn * NKT * 4 * 512 * 8;
  u16*   BhG    = AlG + (size_t)Hn * NKT * 4 * 512 * 8;
  u16*   BlG    = BhG + (size_t)Hn * NKT * 4 * 1024 * 8;
  float* out_exit    = out + (size_t)Bn * Cn;
  float* out_scalars = out + (size_t)Bn * Cn + Bn;

  conv_k<<<dim3(NKT, 12, Hn), 256, 0, stream>>>(feats, W, AhG, AlG, BhG, BlG);
  gemm_k<<<dim3(768, 1, 1), 256, 0, stream>>>(AhG, AlG, BhG, BlG, bias, logits);
  confpick_k<<<Bn, 256, 0, stream>>>(logits, y, out, out_exit, loss_b, corr_b);
  reduce_k<<<1, 256, 0, stream>>>(loss_b, corr_b, out_scalars);
}